// Round 1
// baseline (163.453 us; speedup 1.0000x reference)
//
#include <hip/hip_runtime.h>
#include <math.h>

// Problem constants (B,L,H,D) = (2,4096,8,64); sample_k = n_top = 45
#define B_ 2
#define L_ 4096
#define H_ 8
#define D_ 64
#define S_ 45
#define NTOP_ 45
#define SCALE 0.125f  // 1/sqrt(64)
#define TKEYS 64      // keys per attn block
#define NSPLIT 64     // key splits per (b,h)

// DPP helper: move with compile-time ctrl (quad_perm patterns, butterfly-safe).
template<int CTRL>
__device__ __forceinline__ float dpp_permf(float x) {
    return __int_as_float(__builtin_amdgcn_update_dpp(
        0, __float_as_int(x), CTRL, 0xF, 0xF, true));
}

// ---------------- K1: sparsity measure M = max_s(q.k_s) - sum_s/L ----------------
// NEW: head-PAIR gathers. k[b,j,h,:] and k[b,j,h+1,:] are contiguous (512B), so a
// 32-lane cluster fetches one key row-pair in ONE contiguous request serving 2 heads.
// Same line count as before (experiment: is the 43us ceiling per-line or per-segment?).
// Per-XCD slice = k[b,:,2hp:2hp+2,:] = 2MB -> L2-resident (same budget as before).
// 4096 blocks x 1.5KB LDS -> 8 blocks/CU resident (occupancy 53% -> ~100%).
// Reduce over 16 lanes: DPP quad_perm xor1/xor2 (VALU) + shfl_xor 4/8 (DS).
__global__ __launch_bounds__(256) void compute_M_kernel(
    const float* __restrict__ q, const float* __restrict__ k,
    const int* __restrict__ samp, float* __restrict__ M) {
    __shared__ int sIdx[8 * 48];    // 8 queries x 45 idx + 3 pad
    int tid = threadIdx.x;
    int g   = blockIdx.x;           // 0..4095
    int xcd = g & 7;                // slice id: b = xcd>>2, head-pair = xcd&3
    int chunk = g >> 3;             // 0..511 -> 8 queries each
    int b  = xcd >> 2;
    int h0 = (xcd & 3) * 2;
    int l0 = chunk * 8;

    for (int i = tid; i < 8 * S_; i += 256) {
        int qq = i / S_, ss = i - qq * S_;
        sIdx[qq * 48 + ss] = samp[(long)(l0 + qq) * S_ + ss];
    }
    if (tid < 24) sIdx[(tid / 3) * 48 + S_ + (tid % 3)] = 0;  // pad slots 45..47
    __syncthreads();

    int lane = tid & 63, wave = tid >> 6;
    int c  = lane & 31;             // float4 slot within 512B row-pair
    int q8 = wave * 2 + (lane >> 5);
    int l  = l0 + q8;

    // q row-pair: floats [h0*64 .. h0*64+127]; lane c holds floats 4c..4c+3
    float4 q4 = ((const float4*)(q + (((long)(b * L_ + l)) * H_ + h0) * D_))[c];
    const float4* kb4 = (const float4*)(k + ((long)b * L_ * H_ + h0) * (long)D_);
    const int* myIdx = sIdx + q8 * 48;

    float4 f0 = kb4[(long)myIdx[0] * 128 + c];   // row stride H_*D_/4 = 128 float4
    float4 f1 = kb4[(long)myIdx[1] * 128 + c];
    float4 f2 = kb4[(long)myIdx[2] * 128 + c];

    float vmax = -INFINITY, vsum = 0.f;
    #pragma unroll 3
    for (int s = 0; s < S_; ++s) {
        float4 nf = kb4[(long)myIdx[s + 3] * 128 + c];  // padded tail -> row 0, discarded
        float p = q4.x * f0.x + q4.y * f0.y + q4.z * f0.z + q4.w * f0.w;
        // butterfly sum over 16-lane half-cluster (lanes 0-15 = h0, 16-31 = h1)
        p += dpp_permf<0xB1>(p);        // quad_perm [1,0,3,2] = xor 1
        p += dpp_permf<0x4E>(p);        // quad_perm [2,3,0,1] = xor 2
        p += __shfl_xor(p, 4, 64);
        p += __shfl_xor(p, 8, 64);
        vmax = fmaxf(vmax, p);
        vsum += p;
        f0 = f1; f1 = f2; f2 = nf;
    }
    if ((lane & 15) == 0) {
        int h = h0 + ((lane >> 4) & 1);
        M[(long)(b * 8 + h) * L_ + l] = vmax - vsum * (1.0f / (float)L_);
    }
}

// ---------------- K2: top-45 set per (b,h) via byte-radix select (unchanged) ----------------
__global__ __launch_bounds__(256) void topk_kernel(
    const float* __restrict__ M, int* __restrict__ topIdx) {
    __shared__ unsigned int hist[256];
    __shared__ unsigned int suf[257];
    __shared__ unsigned int wsum[4];
    __shared__ int sBin, sRemain, sCnt, sTieCnt;
    __shared__ int tie[64];

    int bh = blockIdx.x, tid = threadIdx.x;
    int lane = tid & 63, wave = tid >> 6;
    const float* row = M + (long)bh * L_;

    unsigned int key[16];
    #pragma unroll
    for (int j = 0; j < 16; ++j) {
        unsigned int bts = __float_as_uint(row[tid + 256 * j]);
        key[j] = bts ^ ((unsigned int)((int)bts >> 31) | 0x80000000u);
    }

    unsigned int prefix = 0, pmask = 0;
    int remain = NTOP_;
    #pragma unroll 1
    for (int pass = 3; pass >= 0; --pass) {
        int shift = pass * 8;
        hist[tid] = 0;
        __syncthreads();
        #pragma unroll
        for (int j = 0; j < 16; ++j) {
            if ((key[j] & pmask) == prefix)
                atomicAdd(&hist[(key[j] >> shift) & 255u], 1u);
        }
        __syncthreads();
        unsigned int s = hist[tid];
        #pragma unroll
        for (int off = 1; off < 64; off <<= 1) {
            unsigned int o = __shfl_down(s, off, 64);
            if (lane + off < 64) s += o;
        }
        if (lane == 0) wsum[wave] = s;
        __syncthreads();
        unsigned int add = 0;
        for (int w = wave + 1; w < 4; ++w) add += wsum[w];
        s += add;
        suf[tid] = s;
        if (tid == 0) suf[256] = 0;
        __syncthreads();
        if (suf[tid] >= (unsigned int)remain && suf[tid + 1] < (unsigned int)remain) {
            sBin = tid;
            sRemain = remain - (int)suf[tid + 1];
        }
        __syncthreads();
        prefix |= ((unsigned int)sBin) << shift;
        pmask  |= 0xFFu << shift;
        remain  = sRemain;
        __syncthreads();
    }

    if (tid == 0) { sCnt = 0; sTieCnt = 0; }
    __syncthreads();
    int* outRow = topIdx + bh * NTOP_;
    #pragma unroll
    for (int j = 0; j < 16; ++j) {
        int idx = tid + 256 * j;
        if (key[j] > prefix) {
            int pos = atomicAdd(&sCnt, 1);
            outRow[pos] = idx;
        } else if (key[j] == prefix) {
            int tp = atomicAdd(&sTieCnt, 1);
            if (tp < 64) tie[tp] = idx;
        }
    }
    __syncthreads();
    if (tid == 0) {
        int base = sCnt;
        int tc = sTieCnt < 64 ? sTieCnt : 64;
        for (int t = 0; t < remain; ++t) {
            int mi = 0x7fffffff, mj = 0;
            for (int j2 = 0; j2 < tc; ++j2)
                if (tie[j2] < mi) { mi = tie[j2]; mj = j2; }
            outRow[base + t] = mi;
            tie[mj] = 0x7fffffff;
        }
    }
}

// ---------------- K3: key-strip attention (unchanged this round) ----------------
#define STRIDE 68
__global__ __launch_bounds__(256, 2) void attn_strip_kernel(
    const float* __restrict__ q, const float* __restrict__ k,
    const float* __restrict__ v, const int* __restrict__ topIdx,
    float* __restrict__ pOut, float* __restrict__ plPart, int nsplit) {
    __shared__ float sQ[48 * STRIDE];
    __shared__ float sK[TKEYS * STRIDE];
    __shared__ float sV[TKEYS * STRIDE];
    __shared__ float sP[48 * STRIDE];

    int g = blockIdx.x;
    int xcd = g & 7;
    int s0 = g >> 3;
    int grp = s0 / nsplit;
    int bh = xcd + 8 * grp;
    int split = s0 - grp * nsplit;
    int b = bh >> 3, h = bh & 7;
    int tid = threadIdx.x;
    int key0 = split * TKEYS;

    #pragma unroll
    for (int j = 0; j < 3; ++j) {
        int i = tid + 256 * j;
        int u = i >> 4, d4 = i & 15;
        float4 val = make_float4(0.f, 0.f, 0.f, 0.f);
        if (u < NTOP_) {
            int lq = topIdx[bh * NTOP_ + u];
            val = *(const float4*)(q + (((long)(b * L_ + lq)) * H_ + h) * D_ + 4 * d4);
        }
        *(float4*)(sQ + u * STRIDE + 4 * d4) = val;
    }
    #pragma unroll
    for (int j = 0; j < 4; ++j) {
        int i = tid + 256 * j;
        int r = i >> 4, d4 = i & 15;
        long off = (((long)(b * L_ + key0 + r)) * H_ + h) * D_ + 4 * d4;
        *(float4*)(sK + r * STRIDE + 4 * d4) = *(const float4*)(k + off);
        *(float4*)(sV + r * STRIDE + 4 * d4) = *(const float4*)(v + off);
    }
    __syncthreads();

    int tx = tid & 15, ty = tid >> 4;
    float acc[3][4];
    #pragma unroll
    for (int i = 0; i < 3; ++i)
        #pragma unroll
        for (int j = 0; j < 4; ++j) acc[i][j] = 0.f;

    #pragma unroll 4
    for (int d4 = 0; d4 < 16; ++d4) {
        float4 qv[3];
        #pragma unroll
        for (int i = 0; i < 3; ++i)
            qv[i] = *(const float4*)(sQ + (3 * ty + i) * STRIDE + 4 * d4);
        #pragma unroll
        for (int j = 0; j < 4; ++j) {
            float4 kv = *(const float4*)(sK + (tx + 16 * j) * STRIDE + 4 * d4);
            #pragma unroll
            for (int i = 0; i < 3; ++i)
                acc[i][j] += qv[i].x * kv.x + qv[i].y * kv.y + qv[i].z * kv.z + qv[i].w * kv.w;
        }
    }
    #pragma unroll
    for (int i = 0; i < 3; ++i) {
        #pragma unroll
        for (int j = 0; j < 4; ++j)
            sP[(3 * ty + i) * STRIDE + tx + 16 * j] = __expf(acc[i][j] * SCALE);
    }
    __syncthreads();

    int dx = tid & 15, uy = tid >> 4;
    float o[3][4];
    float ls[3];
    #pragma unroll
    for (int i = 0; i < 3; ++i) {
        ls[i] = 0.f;
        #pragma unroll
        for (int c = 0; c < 4; ++c) o[i][c] = 0.f;
    }
    #pragma unroll 4
    for (int k4 = 0; k4 < 16; ++k4) {
        float pa[3][4];
        #pragma unroll
        for (int i = 0; i < 3; ++i)
            *(float4*)pa[i] = *(const float4*)(sP + (3 * uy + i) * STRIDE + 4 * k4);
        #pragma unroll
        for (int c = 0; c < 4; ++c) {
            float4 vr = *(const float4*)(sV + (4 * k4 + c) * STRIDE + 4 * dx);
            #pragma unroll
            for (int i = 0; i < 3; ++i) {
                o[i][0] += pa[i][c] * vr.x;
                o[i][1] += pa[i][c] * vr.y;
                o[i][2] += pa[i][c] * vr.z;
                o[i][3] += pa[i][c] * vr.w;
                ls[i]   += pa[i][c];
            }
        }
    }
    #pragma unroll
    for (int i = 0; i < 3; ++i) {
        int u = 3 * uy + i;
        if (u < NTOP_) {
            long base = ((long)(split * 16 + bh) * NTOP_ + u) * D_;
            *(float4*)(pOut + base + 4 * dx) = make_float4(o[i][0], o[i][1], o[i][2], o[i][3]);
            if (dx == 0) plPart[(long)(split * 16 + bh) * NTOP_ + u] = ls[i];
        }
    }
}

// ---------------- K4': fused zero + split-reduce + normalize + scatter ----------------
// Replaces hipMemsetAsync(16MB) + reduce_norm_kernel (-1 dispatch).
// 256 blocks; block = (b, 32-row l-window) covering all 8 heads: 64KB contiguous output.
// Phase 1: cooperative coalesced zero. Phase 2 (after __syncthreads, which orders
// global writes within the block): each selected (l,h) row handled by one wave,
// lane = d -> fully coalesced 256B reduction loads across nsplit partials.
__global__ __launch_bounds__(256) void zero_reduce_scatter_kernel(
    const int* __restrict__ topIdx, const float* __restrict__ pOut,
    const float* __restrict__ plPart, float* __restrict__ out, int nsplit) {
    __shared__ int sTop[8 * NTOP_];   // this b's 8 head rows of topIdx
    __shared__ int sel[256];          // worst case: 32 l x 8 h all selected
    __shared__ int selCnt;
    int g = blockIdx.x;               // 0..255
    int b = g >> 7;
    int l0 = (g & 127) * 32;
    int tid = threadIdx.x;
    if (tid == 0) selCnt = 0;
    for (int i = tid; i < 8 * NTOP_; i += 256) sTop[i] = topIdx[b * 8 * NTOP_ + i];
    __syncthreads();

    // Phase 1: zero 32*8*64 floats = 4096 float4, coalesced
    float4* obase = (float4*)(out + ((long)(b * L_ + l0)) * H_ * D_);
    float4 z = make_float4(0.f, 0.f, 0.f, 0.f);
    #pragma unroll
    for (int j = 0; j < 16; ++j) obase[tid + 256 * j] = z;

    // membership: thread t -> (l_local = t>>3, h = t&7); topIdx entries are distinct
    {
        int l = l0 + (tid >> 3), h = tid & 7;
        const int* rowp = sTop + h * NTOP_;
        int u = -1;
        #pragma unroll
        for (int t = 0; t < NTOP_; ++t)
            if (rowp[t] == l) u = t;
        if (u >= 0) { int p = atomicAdd(&selCnt, 1); sel[p] = (tid << 8) | u; }
    }
    __syncthreads();   // zeros complete + sel list ready

    // Phase 2: one wave per selected row, lane = d
    int lane = tid & 63, wave = tid >> 6;
    int n = selCnt;
    for (int w = wave; w < n; w += 4) {
        int e = sel[w];
        int t = e >> 8, u = e & 255;
        int l = l0 + (t >> 3), h = t & 7, bh = b * 8 + h;
        // l-sum across splits: lane s reads its partial, butterfly-sum to all lanes
        float lv = (lane < nsplit) ? plPart[((long)lane * 16 + bh) * NTOP_ + u] : 0.f;
        #pragma unroll
        for (int o = 32; o > 0; o >>= 1) lv += __shfl_xor(lv, o, 64);
        float accv = 0.f;
        const float* pb = pOut + ((long)bh * NTOP_ + u) * D_ + lane;
        #pragma unroll 8
        for (int s = 0; s < nsplit; ++s) accv += pb[(long)s * 16 * NTOP_ * D_];
        out[(((long)(b * L_ + l)) * H_ + h) * D_ + lane] = accv / lv;
    }
}

extern "C" void kernel_launch(void* const* d_in, const int* in_sizes, int n_in,
                              void* d_out, int out_size, void* d_ws, size_t ws_size,
                              hipStream_t stream) {
    const float* q = (const float*)d_in[0];
    const float* k = (const float*)d_in[1];
    const float* v = (const float*)d_in[2];
    // d_in[3] = attn_mask (unused)
    const int* samp = (const int*)d_in[4];
    float* out = (float*)d_out;

    char* ws = (char*)d_ws;
    const size_t mBytes   = (size_t)B_ * H_ * L_ * sizeof(float);   // 512 KB
    const size_t topBytes = (size_t)B_ * H_ * NTOP_ * sizeof(int);  // 2880 B
    const size_t plBytes  = (size_t)NSPLIT * 16 * NTOP_ * sizeof(float);
    float* M      = (float*)ws;
    int*   topIdx = (int*)(ws + mBytes);
    float* plPart = (float*)(ws + mBytes + topBytes);
    float* pOut   = (float*)(ws + mBytes + topBytes + plBytes);

    int nsplit = NSPLIT;
    while (nsplit > 1) {
        size_t need = mBytes + topBytes + plBytes +
                      (size_t)nsplit * 16 * NTOP_ * D_ * sizeof(float);
        if (need <= ws_size) break;
        nsplit >>= 1;
    }

    compute_M_kernel<<<4096, 256, 0, stream>>>(q, k, samp, M);

    topk_kernel<<<B_ * H_, 256, 0, stream>>>(M, topIdx);

    attn_strip_kernel<<<nsplit * B_ * H_, 256, 0, stream>>>(
        q, k, v, topIdx, pOut, plPart, nsplit);

    zero_reduce_scatter_kernel<<<B_ * (L_ / 32), 256, 0, stream>>>(
        topIdx, pOut, plPart, out, nsplit);
}